// Round 17
// baseline (254.395 us; speedup 1.0000x reference)
//
#include <hip/hip_runtime.h>

#define D_IN 128
#define D_HID 256
#define D_OUT 128
#define NBIN 10240          // padded bin count (n=10000)
#define HB 256              // histogram/scatter blocks

typedef __attribute__((ext_vector_type(8))) unsigned short ushort8v;
typedef __attribute__((ext_vector_type(4))) unsigned short ushort4v;
typedef __attribute__((ext_vector_type(8))) short short8v;
typedef __attribute__((ext_vector_type(4))) float f32x4;
typedef __attribute__((ext_vector_type(2))) float f32x2;
typedef __attribute__((ext_vector_type(4))) unsigned int uint4v;

__device__ __forceinline__ unsigned short f2bf(float f) {
    unsigned u = __float_as_uint(f);
    unsigned r = (u + 0x7fffu + ((u >> 16) & 1u)) >> 16;
    return (unsigned short)r;
}
__device__ __forceinline__ float bf2f(unsigned short b) {
    return __uint_as_float((unsigned)b << 16);
}
__device__ __forceinline__ unsigned pk_f8x4(float a, float b, float c, float d) {
    int v = __builtin_amdgcn_cvt_pk_fp8_f32(a, b, 0, false);
    v = __builtin_amdgcn_cvt_pk_fp8_f32(c, d, v, true);
    return (unsigned)v;
}
__device__ __forceinline__ unsigned char f8_1(float a) {
    return (unsigned char)(__builtin_amdgcn_cvt_pk_fp8_f32(a, a, 0, false) & 0xff);
}

// ---------------- weight-transpose argument pack ----------------

struct WtrArgs {
    const float* W[6];
    unsigned short* T[6];
    int K[6];
    int N[6];
    const float* xin;
    unsigned short* xout;
    unsigned char* xoutf8;
    int nElem;
};

// ---------------- pass A: per-block LDS histograms + (z=2) weight transposes ----------------

__global__ __launch_bounds__(256) void k_hist(const int* __restrict__ src, const int* __restrict__ dst,
                                              unsigned short* __restrict__ psrc,
                                              unsigned short* __restrict__ pdst,
                                              int E, int EPB, WtrArgs wa, int* __restrict__ done) {
    __shared__ int h[NBIN];
    int b = blockIdx.x, t = threadIdx.x;
    if (blockIdx.y == 2) {
        if (b == 0 && t == 0) *done = 0;    // reset colsum completion counter
        const int starts[7] = {0, 32, 64, 128, 192, 224, 256};
        int m = 0;
        while (b >= starts[m + 1]) ++m;
        int local = b - starts[m];
        int K = wa.K[m], N = wa.N[m];
        int kt = K / 32;
        int k0 = (local % kt) * 32, n0 = (local / kt) * 32;
        float (*tile)[33] = (float(*)[33])h;
        int tx = t & 31, ty = t >> 5;   // 32x8
        const float* W = wa.W[m];
        unsigned short* Wt = wa.T[m];
        for (int i = ty; i < 32; i += 8) tile[i][tx] = W[(size_t)(k0 + i) * N + n0 + tx];
        __syncthreads();
        for (int i = ty; i < 32; i += 8) Wt[(size_t)(n0 + i) * K + k0 + tx] = f2bf(tile[tx][i]);
        // x f32 -> bf16 + fp8, grid-stride
        int stride = HB * 256 * 4;
        for (int i = (b * 256 + t) * 4; i < wa.nElem; i += stride) {
            float4 v = *reinterpret_cast<const float4*>(&wa.xin[i]);
            ushort4v o;
            o[0] = f2bf(v.x); o[1] = f2bf(v.y); o[2] = f2bf(v.z); o[3] = f2bf(v.w);
            *reinterpret_cast<ushort4v*>(&wa.xout[i]) = o;
            *reinterpret_cast<unsigned*>(&wa.xoutf8[i]) = pk_f8x4(v.x, v.y, v.z, v.w);
        }
        return;
    }
    const int* arr = blockIdx.y ? dst : src;
    unsigned short* outp = blockIdx.y ? pdst : psrc;
    for (int i = t; i < NBIN; i += 256) h[i] = 0;
    __syncthreads();
    int beg = b * EPB, end = beg + EPB; if (end > E) end = E;
    for (int e = beg + t; e < end; e += 256)
        atomicAdd(&h[arr[e]], 1);
    __syncthreads();
    for (int i = t; i < NBIN; i += 256)
        outp[(size_t)b * NBIN + i] = (unsigned short)h[i];
}

// ---------------- pass B: parallel column sums + prefix rewrite + (last block) scan ----
// 16 bins/block (grid 640), 16 threads/bin, 16 partials/thread (vc[16] in regs).
// phase 1: per-thread sums; phase 2: 16-wide LDS exclusive prefix;
// phase 3: rewrite pdst from register cache + group base.

__global__ __launch_bounds__(256) void k_colsum(const unsigned short* __restrict__ psrc,
                                                unsigned short* __restrict__ pdst,
                                                float* __restrict__ dis, int* __restrict__ cnt,
                                                int* __restrict__ off, int* __restrict__ done,
                                                int n, int E) {
    __shared__ int sS[16][16];
    __shared__ int sD[16][16];
    int t = threadIdx.x;
    int binL = t & 15, tpb = t >> 4;
    int bin = blockIdx.x * 16 + binL;

    int vc[16];
    int sd = 0, ss = 0;
    #pragma unroll
    for (int k = 0; k < 16; ++k) {
        int b = tpb * 16 + k;
        vc[k] = pdst[(size_t)b * NBIN + bin];
        sd += vc[k];
        ss += psrc[(size_t)b * NBIN + bin];
    }
    sS[tpb][binL] = ss;
    sD[tpb][binL] = sd;
    __syncthreads();
    if (tpb == 0) {
        int running = 0, degs = 0;
        #pragma unroll
        for (int j = 0; j < 16; ++j) {
            degs += sS[j][binL];
            int tmp = sD[j][binL];
            sD[j][binL] = running;
            running += tmp;
        }
        dis[bin] = degs > 0 ? rsqrtf((float)degs) : 0.f;
        cnt[bin] = running;
    }
    __syncthreads();
    int c = sD[tpb][binL];
    #pragma unroll
    for (int k = 0; k < 16; ++k) {
        int b = tpb * 16 + k;
        pdst[(size_t)b * NBIN + bin] = (unsigned short)c;
        c += vc[k];
    }

    // last finished block performs the exclusive scan (saves a dispatch)
    __shared__ int isLast;
    __shared__ int sums[256];
    __threadfence();
    __syncthreads();
    if (t == 0) isLast = (atomicAdd(done, 1) == (int)gridDim.x - 1) ? 1 : 0;
    __syncthreads();
    if (!isLast) return;
    __threadfence();
    int chunk = (n + 255) / 256;
    int beg = t * chunk;
    int end = beg + chunk; if (end > n) end = n;
    int s = 0;
    for (int i = beg; i < end; ++i) s += cnt[i];
    sums[t] = s;
    __syncthreads();
    if (t == 0) {
        int running = 0;
        for (int i = 0; i < 256; ++i) { int tmp = sums[i]; sums[i] = running; running += tmp; }
        off[n] = E;
        *done = 0;                      // reset for next replay
    }
    __syncthreads();
    int pre = sums[t];
    for (int i = beg; i < end; ++i) { off[i] = pre; pre += cnt[i]; }
}

// ---------------- pass C: scatter (LDS rank, no global atomics) ----------------

__global__ __launch_bounds__(256) void k_scatter2(const int* __restrict__ src, const int* __restrict__ dst,
                                                  const float* __restrict__ dis, const int* __restrict__ off,
                                                  const unsigned short* __restrict__ pfx,
                                                  unsigned* __restrict__ edges, int E, int EPB) {
    __shared__ int lcnt[NBIN];
    int b = blockIdx.x, t = threadIdx.x;
    for (int i = t; i < NBIN; i += 256) lcnt[i] = 0;
    __syncthreads();
    int beg = b * EPB, end = beg + EPB; if (end > E) end = E;
    const unsigned short* pf = pfx + (size_t)b * NBIN;
    for (int e = beg + t; e < end; e += 256) {
        int s = src[e], d = dst[e];
        int r = atomicAdd(&lcnt[d], 1);
        int pos = off[d] + (int)pf[d] + r;
        float nv = -(dis[s] * dis[d]);
        edges[pos] = ((unsigned)s << 16) | (unsigned)f2bf(nv);
    }
}

// ---------------- CSR gather-aggregate, fp8 input, single pass over D ----------------

#define AGG_GATHER(eSet, vSet)                                                        \
    _Pragma("unroll")                                                                 \
    for (int u = 0; u < 8; ++u)                                                       \
        vSet[u] = *reinterpret_cast<const uint4v*>(&xf8[(size_t)(eSet[u] >> 16) * D + cbase]);

#define AGG_ACCUM(eSet, vSet)                                                         \
    _Pragma("unroll")                                                                 \
    for (int u = 0; u < 8; ++u) {                                                     \
        float nv = __uint_as_float(eSet[u] << 16);                                    \
        _Pragma("unroll")                                                             \
        for (int d = 0; d < 4; ++d) {                                                 \
            f32x2 lo = __builtin_amdgcn_cvt_pk_f32_fp8((int)vSet[u][d], false);       \
            f32x2 hi = __builtin_amdgcn_cvt_pk_f32_fp8((int)vSet[u][d], true);        \
            acc[4*d+0] += nv * lo[0]; acc[4*d+1] += nv * lo[1];                       \
            acc[4*d+2] += nv * hi[0]; acc[4*d+3] += nv * hi[1];                       \
        }                                                                             \
    }

#define AGG_ONE(e)                                                                    \
    {                                                                                 \
        float nv = __uint_as_float((e) << 16);                                        \
        uint4v v = *reinterpret_cast<const uint4v*>(&xf8[(size_t)((e) >> 16) * D + cbase]); \
        _Pragma("unroll")                                                             \
        for (int d = 0; d < 4; ++d) {                                                 \
            f32x2 lo = __builtin_amdgcn_cvt_pk_f32_fp8((int)v[d], false);             \
            f32x2 hi = __builtin_amdgcn_cvt_pk_f32_fp8((int)v[d], true);              \
            acc[4*d+0] += nv * lo[0]; acc[4*d+1] += nv * lo[1];                       \
            acc[4*d+2] += nv * hi[0]; acc[4*d+3] += nv * hi[1];                       \
        }                                                                             \
    }

template<int D, bool STBF, bool STF32, bool ADDB>
__global__ __launch_bounds__(256) void k_agg_f8(const int* __restrict__ off,
                                                const unsigned* __restrict__ edges,
                                                const unsigned char* __restrict__ xf8,
                                                unsigned short* __restrict__ outb,
                                                float* __restrict__ outf,
                                                const float* __restrict__ base, int n) {
    const int TPN = D / 16;
    const int NPB = 256 / TPN;
    int tid = threadIdx.x;
    int node = blockIdx.x * NPB + tid / TPN;
    if (node >= n) return;
    int cbase = (tid % TPN) * 16;
    int i = off[node], end = off[node + 1];
    float acc[16] = {};
    int nb = (end - i) >> 3;

    if (nb > 0) {
        unsigned e0[8], e1[8];
        uint4v v0[8], v1[8];
        #pragma unroll
        for (int u = 0; u < 8; ++u) e0[u] = edges[i + u];
        AGG_GATHER(e0, v0)
        int b = 1;
        for (; b + 1 < nb; b += 2) {
            int base1 = i + b * 8;
            #pragma unroll
            for (int u = 0; u < 8; ++u) e1[u] = edges[base1 + u];
            AGG_GATHER(e1, v1)
            AGG_ACCUM(e0, v0)
            int base0 = i + (b + 1) * 8;
            #pragma unroll
            for (int u = 0; u < 8; ++u) e0[u] = edges[base0 + u];
            AGG_GATHER(e0, v0)
            AGG_ACCUM(e1, v1)
        }
        if (b < nb) {
            int base1 = i + b * 8;
            #pragma unroll
            for (int u = 0; u < 8; ++u) e1[u] = edges[base1 + u];
            AGG_GATHER(e1, v1)
            AGG_ACCUM(e0, v0)
            AGG_ACCUM(e1, v1)
        } else {
            AGG_ACCUM(e0, v0)
        }
    }
    for (int t = i + nb * 8; t < end; ++t) {
        unsigned e = edges[t];
        AGG_ONE(e)
    }

    if (ADDB) {
        #pragma unroll
        for (int q = 0; q < 4; ++q) {
            float4 bq = *reinterpret_cast<const float4*>(&base[(size_t)node * D + cbase + q * 4]);
            acc[q*4+0] += bq.x; acc[q*4+1] += bq.y; acc[q*4+2] += bq.z; acc[q*4+3] += bq.w;
        }
    }
    if (STBF) {
        ushort8v ob0, ob1;
        #pragma unroll
        for (int j = 0; j < 8; ++j) { ob0[j] = f2bf(acc[j]); ob1[j] = f2bf(acc[8 + j]); }
        *reinterpret_cast<ushort8v*>(&outb[(size_t)node * D + cbase]) = ob0;
        *reinterpret_cast<ushort8v*>(&outb[(size_t)node * D + cbase + 8]) = ob1;
    }
    if (STF32) {
        #pragma unroll
        for (int q = 0; q < 4; ++q) {
            float4 o;
            o.x = acc[q*4+0]; o.y = acc[q*4+1]; o.z = acc[q*4+2]; o.w = acc[q*4+3];
            *reinterpret_cast<float4*>(&outf[(size_t)node * D + cbase + q * 4]) = o;
        }
    }
}

// ---------------- MFMA bf16 GEMM, sequential dual passes, BK=64 ----------------

#define LDT 72

template<int K, bool RELU, bool HAS_B2, bool HAS_BIAS, bool ST_BF, bool ST_F8>
__global__ __launch_bounds__(256) void k_gemm_mfma(
        const unsigned short* __restrict__ A1, const unsigned short* __restrict__ W0t,
        const unsigned short* __restrict__ A2, const unsigned short* __restrict__ W1t,
        const float* __restrict__ bias,
        unsigned short* __restrict__ Cb, unsigned char* __restrict__ Cf8, int M, int N) {
    __shared__ unsigned short As[64 * LDT];
    __shared__ unsigned short Bs[128 * LDT];
    int tid = threadIdx.x, lane = tid & 63, wave = tid >> 6;
    int wm = wave >> 1, wn = wave & 1;
    int row0 = blockIdx.x * 64, col0 = blockIdx.y * 128;
    f32x4 acc[2][4];
    #pragma unroll
    for (int i = 0; i < 2; ++i)
        #pragma unroll
        for (int j = 0; j < 4; ++j)
            acc[i][j] = (f32x4){0.f, 0.f, 0.f, 0.f};

    int aRow = wm * 32 + (lane & 15);
    int bRow = wn * 64 + (lane & 15);
    int kOff = (lane >> 4) * 8;
    int sr = tid >> 2, sc = (tid & 3) * 8;
    int gra = row0 + sr; if (gra >= M) gra = M - 1;

    const int npass = HAS_B2 ? 2 : 1;
    for (int pass = 0; pass < npass; ++pass) {
        const unsigned short* A = pass ? A2 : A1;
        const unsigned short* W = pass ? W1t : W0t;
        for (int k0 = 0; k0 < K; k0 += 64) {
            #pragma unroll
            for (int h = 0; h < 2; ++h) {
                ushort8v va = *reinterpret_cast<const ushort8v*>(&A[(size_t)gra * K + k0 + sc + h * 32]);
                *reinterpret_cast<ushort8v*>(&As[sr * LDT + sc + h * 32]) = va;
            }
            #pragma unroll
            for (int g = 0; g < 2; ++g)
                #pragma unroll
                for (int h = 0; h < 2; ++h) {
                    int r = sr + g * 64;
                    ushort8v vb = *reinterpret_cast<const ushort8v*>(&W[(size_t)(col0 + r) * K + k0 + sc + h * 32]);
                    *reinterpret_cast<ushort8v*>(&Bs[r * LDT + sc + h * 32]) = vb;
                }
            __syncthreads();
            #pragma unroll
            for (int kk = 0; kk < 2; ++kk) {
                int ko = kOff + kk * 32;
                short8v a[2], bb[4];
                #pragma unroll
                for (int i = 0; i < 2; ++i)
                    a[i] = *reinterpret_cast<const short8v*>(&As[(aRow + i * 16) * LDT + ko]);
                #pragma unroll
                for (int i = 0; i < 4; ++i)
                    bb[i] = *reinterpret_cast<const short8v*>(&Bs[(bRow + i * 16) * LDT + ko]);
                #pragma unroll
                for (int mi = 0; mi < 2; ++mi)
                    #pragma unroll
                    for (int ni = 0; ni < 4; ++ni)
                        acc[mi][ni] = __builtin_amdgcn_mfma_f32_16x16x32_bf16(a[mi], bb[ni], acc[mi][ni], 0, 0, 0);
            }
            __syncthreads();
        }
    }

    int colBase = col0 + wn * 64 + (lane & 15);
    int rowSub = (lane >> 4) * 4;
    #pragma unroll
    for (int mi = 0; mi < 2; ++mi) {
        int rowF = row0 + wm * 32 + mi * 16 + rowSub;
        #pragma unroll
        for (int r = 0; r < 4; ++r) {
            int gr = rowF + r;
            if (gr < M) {
                #pragma unroll
                for (int ni = 0; ni < 4; ++ni) {
                    int gc = colBase + ni * 16;
                    float v = acc[mi][ni][r];
                    if (HAS_BIAS) v += bias[gc];
                    if (RELU)     v = fmaxf(v, 0.f);
                    if (ST_BF)    Cb[(size_t)gr * N + gc] = f2bf(v);
                    if (ST_F8)    Cf8[(size_t)gr * N + gc] = f8_1(v);
                }
            }
        }
    }
}

// ---------------- dual GEMM for layer 3 ----------------
// blockIdx.y==0: part = h2@W03 + b3 (fp32); blockIdx.y==1: y3 = h2@W13 (fp8).

template<int K>
__global__ __launch_bounds__(256) void k_gemm_dual(
        const unsigned short* __restrict__ A1, const unsigned short* __restrict__ W03t,
        const unsigned short* __restrict__ W13t, const float* __restrict__ bias,
        float* __restrict__ part, unsigned char* __restrict__ y3f8, int M) {
    const int N = 128;
    __shared__ unsigned short As[64 * LDT];
    __shared__ unsigned short Bs[128 * LDT];
    int tid = threadIdx.x, lane = tid & 63, wave = tid >> 6;
    int wm = wave >> 1, wn = wave & 1;
    int row0 = blockIdx.x * 64;
    const unsigned short* W = blockIdx.y ? W13t : W03t;
    f32x4 acc[2][4];
    #pragma unroll
    for (int i = 0; i < 2; ++i)
        #pragma unroll
        for (int j = 0; j < 4; ++j)
            acc[i][j] = (f32x4){0.f, 0.f, 0.f, 0.f};

    int aRow = wm * 32 + (lane & 15);
    int bRow = wn * 64 + (lane & 15);
    int kOff = (lane >> 4) * 8;
    int sr = tid >> 2, sc = (tid & 3) * 8;
    int gra = row0 + sr; if (gra >= M) gra = M - 1;

    for (int k0 = 0; k0 < K; k0 += 64) {
        #pragma unroll
        for (int h = 0; h < 2; ++h) {
            ushort8v va = *reinterpret_cast<const ushort8v*>(&A1[(size_t)gra * K + k0 + sc + h * 32]);
            *reinterpret_cast<ushort8v*>(&As[sr * LDT + sc + h * 32]) = va;
        }
        #pragma unroll
        for (int g = 0; g < 2; ++g)
            #pragma unroll
            for (int h = 0; h < 2; ++h) {
                int r = sr + g * 64;
                ushort8v vb = *reinterpret_cast<const ushort8v*>(&W[(size_t)r * K + k0 + sc + h * 32]);
                *reinterpret_cast<ushort8v*>(&Bs[r * LDT + sc + h * 32]) = vb;
            }
        __syncthreads();
        #pragma unroll
        for (int kk = 0; kk < 2; ++kk) {
            int ko = kOff + kk * 32;
            short8v a[2], bb[4];
            #pragma unroll
            for (int i = 0; i < 2; ++i)
                a[i] = *reinterpret_cast<const short8v*>(&As[(aRow + i * 16) * LDT + ko]);
            #pragma unroll
            for (int i = 0; i < 4; ++i)
                bb[i] = *reinterpret_cast<const short8v*>(&Bs[(bRow + i * 16) * LDT + ko]);
            #pragma unroll
            for (int mi = 0; mi < 2; ++mi)
                #pragma unroll
                for (int ni = 0; ni < 4; ++ni)
                    acc[mi][ni] = __builtin_amdgcn_mfma_f32_16x16x32_bf16(a[mi], bb[ni], acc[mi][ni], 0, 0, 0);
        }
        __syncthreads();
    }

    int colBase = wn * 64 + (lane & 15);
    int rowSub = (lane >> 4) * 4;
    bool isPart = (blockIdx.y == 0);
    #pragma unroll
    for (int mi = 0; mi < 2; ++mi) {
        int rowF = row0 + wm * 32 + mi * 16 + rowSub;
        #pragma unroll
        for (int r = 0; r < 4; ++r) {
            int gr = rowF + r;
            if (gr < M) {
                #pragma unroll
                for (int ni = 0; ni < 4; ++ni) {
                    int gc = colBase + ni * 16;
                    float v = acc[mi][ni][r];
                    if (isPart) part[(size_t)gr * N + gc] = v + bias[gc];
                    else        y3f8[(size_t)gr * N + gc] = f8_1(v);
                }
            }
        }
    }
}

// ---------------- launch ----------------

extern "C" void kernel_launch(void* const* d_in, const int* in_sizes, int n_in,
                              void* d_out, int out_size, void* d_ws, size_t ws_size,
                              hipStream_t stream) {
    const float* x   = (const float*)d_in[0];
    const int*   ei  = (const int*)d_in[1];
    const float* W01 = (const float*)d_in[3];
    const float* W11 = (const float*)d_in[4];
    const float* b1  = (const float*)d_in[5];
    const float* W02 = (const float*)d_in[6];
    const float* W12 = (const float*)d_in[7];
    const float* b2  = (const float*)d_in[8];
    const float* W03 = (const float*)d_in[9];
    const float* W13 = (const float*)d_in[10];
    const float* b3  = (const float*)d_in[11];
    float* out = (float*)d_out;

    const int n = in_sizes[0] / D_IN;   // 10000
    const int E = in_sizes[1] / 2;      // 640000
    const int* src = ei;
    const int* dst = ei + E;
    const int EPB = (E + HB - 1) / HB;  // 2500

    char* wsb = (char*)d_ws;
    float* dis   = (float*)wsb;                   wsb += NBIN * 4;
    int*   cnt   = (int*)wsb;                     wsb += NBIN * 4;
    int*   off   = (int*)wsb;                     wsb += (NBIN + 16) * 4;
    int*   done  = (int*)wsb;                     wsb += 16;
    unsigned short* psrc = (unsigned short*)wsb;  wsb += (size_t)HB * NBIN * 2;
    unsigned short* pdst = (unsigned short*)wsb;  wsb += (size_t)HB * NBIN * 2;
    unsigned* edges = (unsigned*)wsb;             wsb += (size_t)E * 4;
    unsigned short* txb  = (unsigned short*)wsb;  wsb += (size_t)n * D_HID * 2;
    float*          part = (float*)wsb;           wsb += (size_t)n * D_OUT * 4;
    unsigned short* x_bf = (unsigned short*)wsb;  wsb += (size_t)n * D_IN * 2;
    unsigned short* h1_bf = (unsigned short*)wsb; wsb += (size_t)n * D_HID * 2;
    unsigned short* h2_bf = (unsigned short*)wsb; wsb += (size_t)n * D_HID * 2;
    unsigned char* x_f8  = (unsigned char*)wsb;   wsb += (size_t)n * D_IN;
    unsigned char* h1_f8 = (unsigned char*)wsb;   wsb += (size_t)n * D_HID;
    unsigned char* y3_f8 = (unsigned char*)wsb;   wsb += (size_t)n * D_OUT;
    wsb = (char*)(((size_t)wsb + 255) & ~(size_t)255);
    unsigned short* W01t = (unsigned short*)wsb;  wsb += (size_t)D_IN  * D_HID * 2;
    unsigned short* W11t = (unsigned short*)wsb;  wsb += (size_t)D_IN  * D_HID * 2;
    unsigned short* W02t = (unsigned short*)wsb;  wsb += (size_t)D_HID * D_HID * 2;
    unsigned short* W12t = (unsigned short*)wsb;  wsb += (size_t)D_HID * D_HID * 2;
    unsigned short* W03t = (unsigned short*)wsb;  wsb += (size_t)D_HID * D_OUT * 2;
    unsigned short* W13t = (unsigned short*)wsb;  wsb += (size_t)D_HID * D_OUT * 2;

    const int gmx = (n + 63) / 64;      // 157 M-tiles
    const int ga128 = (n + 31) / 32;    // 313 blocks (TPN=8)
    const int ga256 = (n + 15) / 16;    // 625 blocks (TPN=16)

    WtrArgs wa;
    wa.W[0] = W01; wa.T[0] = W01t; wa.K[0] = D_IN;  wa.N[0] = D_HID;
    wa.W[1] = W11; wa.T[1] = W11t; wa.K[1] = D_IN;  wa.N[1] = D_HID;
    wa.W[2] = W02; wa.T[2] = W02t; wa.K[2] = D_HID; wa.N[2] = D_HID;
    wa.W[3] = W12; wa.T[3] = W12t; wa.K[3] = D_HID; wa.N[3] = D_HID;
    wa.W[4] = W03; wa.T[4] = W03t; wa.K[4] = D_HID; wa.N[4] = D_OUT;
    wa.W[5] = W13; wa.T[5] = W13t; wa.K[5] = D_HID; wa.N[5] = D_OUT;
    wa.xin = x; wa.xout = x_bf; wa.xoutf8 = x_f8; wa.nElem = n * D_IN;

    // ---- CSR build (atomic-free) + normalization + conversions ----
    k_hist<<<dim3(HB, 3), 256, 0, stream>>>(src, dst, psrc, pdst, E, EPB, wa, done);
    k_colsum<<<NBIN / 16, 256, 0, stream>>>(psrc, pdst, dis, cnt, off, done, n, E);
    k_scatter2<<<HB, 256, 0, stream>>>(src, dst, dis, off, pdst, edges, E, EPB);

    // ---- layer 1: h1 = relu(x@W01 + (A x)@W11 + b1) ----
    k_agg_f8<D_IN, true, false, false><<<ga128, 256, 0, stream>>>(
        off, edges, x_f8, txb, nullptr, nullptr, n);
    k_gemm_mfma<D_IN, true, true, true, true, true><<<dim3(gmx, D_HID / 128), 256, 0, stream>>>(
        x_bf, W01t, txb, W11t, b1, h1_bf, h1_f8, n, D_HID);

    // ---- layer 2: h2 = relu(h1@W02 + (A h1)@W12 + b2) ----
    k_agg_f8<D_HID, true, false, false><<<ga256, 256, 0, stream>>>(
        off, edges, h1_f8, txb, nullptr, nullptr, n);
    k_gemm_mfma<D_HID, true, true, true, true, false><<<dim3(gmx, D_HID / 128), 256, 0, stream>>>(
        h1_bf, W02t, txb, W12t, b2, h2_bf, nullptr, n, D_HID);

    // ---- layer 3: out = (h2@W03 + b3) + A (h2@W13) ----
    k_gemm_dual<D_HID><<<dim3(gmx, 2), 256, 0, stream>>>(
        h2_bf, W03t, W13t, b3, part, y3_f8, n);
    k_agg_f8<D_OUT, false, true, true><<<ga128, 256, 0, stream>>>(
        off, edges, y3_f8, nullptr, out, part, n);
}

// Round 18
// 148.902 us; speedup vs baseline: 1.7085x; 1.7085x over previous
//
#include <hip/hip_runtime.h>

#define D_IN 128
#define D_HID 256
#define D_OUT 128
#define NBIN 10240          // padded bin count (n=10000)
#define HB 256              // histogram/scatter blocks

typedef __attribute__((ext_vector_type(8))) unsigned short ushort8v;
typedef __attribute__((ext_vector_type(4))) unsigned short ushort4v;
typedef __attribute__((ext_vector_type(8))) short short8v;
typedef __attribute__((ext_vector_type(4))) float f32x4;
typedef __attribute__((ext_vector_type(2))) float f32x2;
typedef __attribute__((ext_vector_type(4))) unsigned int uint4v;

__device__ __forceinline__ unsigned short f2bf(float f) {
    unsigned u = __float_as_uint(f);
    unsigned r = (u + 0x7fffu + ((u >> 16) & 1u)) >> 16;
    return (unsigned short)r;
}
__device__ __forceinline__ float bf2f(unsigned short b) {
    return __uint_as_float((unsigned)b << 16);
}
__device__ __forceinline__ unsigned pk_f8x4(float a, float b, float c, float d) {
    int v = __builtin_amdgcn_cvt_pk_fp8_f32(a, b, 0, false);
    v = __builtin_amdgcn_cvt_pk_fp8_f32(c, d, v, true);
    return (unsigned)v;
}
__device__ __forceinline__ unsigned char f8_1(float a) {
    return (unsigned char)(__builtin_amdgcn_cvt_pk_fp8_f32(a, a, 0, false) & 0xff);
}

// ---------------- weight-transpose argument pack ----------------

struct WtrArgs {
    const float* W[6];
    unsigned short* T[6];
    int K[6];
    int N[6];
    const float* xin;
    unsigned short* xout;
    unsigned char* xoutf8;
    int nElem;
};

// ---------------- pass A: per-block LDS histograms + (z=2) weight transposes ----------------

__global__ __launch_bounds__(256) void k_hist(const int* __restrict__ src, const int* __restrict__ dst,
                                              unsigned short* __restrict__ psrc,
                                              unsigned short* __restrict__ pdst,
                                              int E, int EPB, WtrArgs wa) {
    __shared__ int h[NBIN];
    int b = blockIdx.x, t = threadIdx.x;
    if (blockIdx.y == 2) {
        const int starts[7] = {0, 32, 64, 128, 192, 224, 256};
        int m = 0;
        while (b >= starts[m + 1]) ++m;
        int local = b - starts[m];
        int K = wa.K[m], N = wa.N[m];
        int kt = K / 32;
        int k0 = (local % kt) * 32, n0 = (local / kt) * 32;
        float (*tile)[33] = (float(*)[33])h;
        int tx = t & 31, ty = t >> 5;   // 32x8
        const float* W = wa.W[m];
        unsigned short* Wt = wa.T[m];
        for (int i = ty; i < 32; i += 8) tile[i][tx] = W[(size_t)(k0 + i) * N + n0 + tx];
        __syncthreads();
        for (int i = ty; i < 32; i += 8) Wt[(size_t)(n0 + i) * K + k0 + tx] = f2bf(tile[tx][i]);
        // x f32 -> bf16 + fp8, grid-stride
        int stride = HB * 256 * 4;
        for (int i = (b * 256 + t) * 4; i < wa.nElem; i += stride) {
            float4 v = *reinterpret_cast<const float4*>(&wa.xin[i]);
            ushort4v o;
            o[0] = f2bf(v.x); o[1] = f2bf(v.y); o[2] = f2bf(v.z); o[3] = f2bf(v.w);
            *reinterpret_cast<ushort4v*>(&wa.xout[i]) = o;
            *reinterpret_cast<unsigned*>(&wa.xoutf8[i]) = pk_f8x4(v.x, v.y, v.z, v.w);
        }
        return;
    }
    const int* arr = blockIdx.y ? dst : src;
    unsigned short* outp = blockIdx.y ? pdst : psrc;
    for (int i = t; i < NBIN; i += 256) h[i] = 0;
    __syncthreads();
    int beg = b * EPB, end = beg + EPB; if (end > E) end = E;
    for (int e = beg + t; e < end; e += 256)
        atomicAdd(&h[arr[e]], 1);
    __syncthreads();
    for (int i = t; i < NBIN; i += 256)
        outp[(size_t)b * NBIN + i] = (unsigned short)h[i];
}

// ---------------- pass B: parallel column sums + prefix rewrite ----------------
// 64 bins/block (grid 160). Wave covers 64 consecutive bins -> 128B coalesced loads.
// g = t>>6 selects one of 4 partial-groups (64 partials each). No per-thread arrays:
// phase 2 re-reads pdst (L2-resident) while rewriting the exclusive prefix.

__global__ __launch_bounds__(256) void k_colsum(const unsigned short* __restrict__ psrc,
                                                unsigned short* __restrict__ pdst,
                                                float* __restrict__ dis, int* __restrict__ cnt) {
    __shared__ int sS[4][64];
    __shared__ int sD[4][64];
    int t = threadIdx.x;
    int binL = t & 63, g = t >> 6;
    int bin = blockIdx.x * 64 + binL;

    int ss = 0, sd = 0;
    #pragma unroll 8
    for (int k = 0; k < 64; ++k) {
        int b = g * 64 + k;
        ss += psrc[(size_t)b * NBIN + bin];
        sd += pdst[(size_t)b * NBIN + bin];
    }
    sS[g][binL] = ss;
    sD[g][binL] = sd;
    __syncthreads();
    if (g == 0) {
        int degs = sS[0][binL] + sS[1][binL] + sS[2][binL] + sS[3][binL];
        int ctot = sD[0][binL] + sD[1][binL] + sD[2][binL] + sD[3][binL];
        dis[bin] = degs > 0 ? rsqrtf((float)degs) : 0.f;
        cnt[bin] = ctot;
    }
    int base = 0;
    #pragma unroll
    for (int gg = 0; gg < 4; ++gg)
        if (gg < g) base += sD[gg][binL];
    int c = base;
    #pragma unroll 8
    for (int k = 0; k < 64; ++k) {
        int b = g * 64 + k;
        int v = pdst[(size_t)b * NBIN + bin];
        pdst[(size_t)b * NBIN + bin] = (unsigned short)c;
        c += v;
    }
}

// ---------------- exclusive scan (single block) ----------------

__global__ void k_scan(const int* __restrict__ cnt, int* __restrict__ off, int n, int E) {
    __shared__ int sums[256];
    int t = threadIdx.x;
    int chunk = (n + 255) / 256;
    int beg = t * chunk;
    int end = beg + chunk; if (end > n) end = n;
    int s = 0;
    for (int i = beg; i < end; ++i) s += cnt[i];
    sums[t] = s;
    __syncthreads();
    if (t == 0) {
        int running = 0;
        for (int i = 0; i < 256; ++i) { int tmp = sums[i]; sums[i] = running; running += tmp; }
        off[n] = E;
    }
    __syncthreads();
    int pre = sums[t];
    for (int i = beg; i < end; ++i) { off[i] = pre; pre += cnt[i]; }
}

// ---------------- pass C: scatter (LDS rank, no global atomics) ----------------

__global__ __launch_bounds__(256) void k_scatter2(const int* __restrict__ src, const int* __restrict__ dst,
                                                  const float* __restrict__ dis, const int* __restrict__ off,
                                                  const unsigned short* __restrict__ pfx,
                                                  unsigned* __restrict__ edges, int E, int EPB) {
    __shared__ int lcnt[NBIN];
    int b = blockIdx.x, t = threadIdx.x;
    for (int i = t; i < NBIN; i += 256) lcnt[i] = 0;
    __syncthreads();
    int beg = b * EPB, end = beg + EPB; if (end > E) end = E;
    const unsigned short* pf = pfx + (size_t)b * NBIN;
    for (int e = beg + t; e < end; e += 256) {
        int s = src[e], d = dst[e];
        int r = atomicAdd(&lcnt[d], 1);
        int pos = off[d] + (int)pf[d] + r;
        float nv = -(dis[s] * dis[d]);
        edges[pos] = ((unsigned)s << 16) | (unsigned)f2bf(nv);
    }
}

// ---------------- CSR gather-aggregate, fp8 input, single pass over D ----------------

#define AGG_GATHER(eSet, vSet)                                                        \
    _Pragma("unroll")                                                                 \
    for (int u = 0; u < 8; ++u)                                                       \
        vSet[u] = *reinterpret_cast<const uint4v*>(&xf8[(size_t)(eSet[u] >> 16) * D + cbase]);

#define AGG_ACCUM(eSet, vSet)                                                         \
    _Pragma("unroll")                                                                 \
    for (int u = 0; u < 8; ++u) {                                                     \
        float nv = __uint_as_float(eSet[u] << 16);                                    \
        _Pragma("unroll")                                                             \
        for (int d = 0; d < 4; ++d) {                                                 \
            f32x2 lo = __builtin_amdgcn_cvt_pk_f32_fp8((int)vSet[u][d], false);       \
            f32x2 hi = __builtin_amdgcn_cvt_pk_f32_fp8((int)vSet[u][d], true);        \
            acc[4*d+0] += nv * lo[0]; acc[4*d+1] += nv * lo[1];                       \
            acc[4*d+2] += nv * hi[0]; acc[4*d+3] += nv * hi[1];                       \
        }                                                                             \
    }

#define AGG_ONE(e)                                                                    \
    {                                                                                 \
        float nv = __uint_as_float((e) << 16);                                        \
        uint4v v = *reinterpret_cast<const uint4v*>(&xf8[(size_t)((e) >> 16) * D + cbase]); \
        _Pragma("unroll")                                                             \
        for (int d = 0; d < 4; ++d) {                                                 \
            f32x2 lo = __builtin_amdgcn_cvt_pk_f32_fp8((int)v[d], false);             \
            f32x2 hi = __builtin_amdgcn_cvt_pk_f32_fp8((int)v[d], true);              \
            acc[4*d+0] += nv * lo[0]; acc[4*d+1] += nv * lo[1];                       \
            acc[4*d+2] += nv * hi[0]; acc[4*d+3] += nv * hi[1];                       \
        }                                                                             \
    }

template<int D, bool STBF, bool STF32, bool ADDB>
__global__ __launch_bounds__(256) void k_agg_f8(const int* __restrict__ off,
                                                const unsigned* __restrict__ edges,
                                                const unsigned char* __restrict__ xf8,
                                                unsigned short* __restrict__ outb,
                                                float* __restrict__ outf,
                                                const float* __restrict__ base, int n) {
    const int TPN = D / 16;
    const int NPB = 256 / TPN;
    int tid = threadIdx.x;
    int node = blockIdx.x * NPB + tid / TPN;
    if (node >= n) return;
    int cbase = (tid % TPN) * 16;
    int i = off[node], end = off[node + 1];
    float acc[16] = {};
    int nb = (end - i) >> 3;

    if (nb > 0) {
        unsigned e0[8], e1[8];
        uint4v v0[8], v1[8];
        #pragma unroll
        for (int u = 0; u < 8; ++u) e0[u] = edges[i + u];
        AGG_GATHER(e0, v0)
        int b = 1;
        for (; b + 1 < nb; b += 2) {
            int base1 = i + b * 8;
            #pragma unroll
            for (int u = 0; u < 8; ++u) e1[u] = edges[base1 + u];
            AGG_GATHER(e1, v1)
            AGG_ACCUM(e0, v0)
            int base0 = i + (b + 1) * 8;
            #pragma unroll
            for (int u = 0; u < 8; ++u) e0[u] = edges[base0 + u];
            AGG_GATHER(e0, v0)
            AGG_ACCUM(e1, v1)
        }
        if (b < nb) {
            int base1 = i + b * 8;
            #pragma unroll
            for (int u = 0; u < 8; ++u) e1[u] = edges[base1 + u];
            AGG_GATHER(e1, v1)
            AGG_ACCUM(e0, v0)
            AGG_ACCUM(e1, v1)
        } else {
            AGG_ACCUM(e0, v0)
        }
    }
    for (int t = i + nb * 8; t < end; ++t) {
        unsigned e = edges[t];
        AGG_ONE(e)
    }

    if (ADDB) {
        #pragma unroll
        for (int q = 0; q < 4; ++q) {
            float4 bq = *reinterpret_cast<const float4*>(&base[(size_t)node * D + cbase + q * 4]);
            acc[q*4+0] += bq.x; acc[q*4+1] += bq.y; acc[q*4+2] += bq.z; acc[q*4+3] += bq.w;
        }
    }
    if (STBF) {
        ushort8v ob0, ob1;
        #pragma unroll
        for (int j = 0; j < 8; ++j) { ob0[j] = f2bf(acc[j]); ob1[j] = f2bf(acc[8 + j]); }
        *reinterpret_cast<ushort8v*>(&outb[(size_t)node * D + cbase]) = ob0;
        *reinterpret_cast<ushort8v*>(&outb[(size_t)node * D + cbase + 8]) = ob1;
    }
    if (STF32) {
        #pragma unroll
        for (int q = 0; q < 4; ++q) {
            float4 o;
            o.x = acc[q*4+0]; o.y = acc[q*4+1]; o.z = acc[q*4+2]; o.w = acc[q*4+3];
            *reinterpret_cast<float4*>(&outf[(size_t)node * D + cbase + q * 4]) = o;
        }
    }
}

// ---------------- MFMA bf16 GEMM, sequential dual passes, BK=64 ----------------

#define LDT 72

template<int K, bool RELU, bool HAS_B2, bool HAS_BIAS, bool ST_BF, bool ST_F8>
__global__ __launch_bounds__(256) void k_gemm_mfma(
        const unsigned short* __restrict__ A1, const unsigned short* __restrict__ W0t,
        const unsigned short* __restrict__ A2, const unsigned short* __restrict__ W1t,
        const float* __restrict__ bias,
        unsigned short* __restrict__ Cb, unsigned char* __restrict__ Cf8, int M, int N) {
    __shared__ unsigned short As[64 * LDT];
    __shared__ unsigned short Bs[128 * LDT];
    int tid = threadIdx.x, lane = tid & 63, wave = tid >> 6;
    int wm = wave >> 1, wn = wave & 1;
    int row0 = blockIdx.x * 64, col0 = blockIdx.y * 128;
    f32x4 acc[2][4];
    #pragma unroll
    for (int i = 0; i < 2; ++i)
        #pragma unroll
        for (int j = 0; j < 4; ++j)
            acc[i][j] = (f32x4){0.f, 0.f, 0.f, 0.f};

    int aRow = wm * 32 + (lane & 15);
    int bRow = wn * 64 + (lane & 15);
    int kOff = (lane >> 4) * 8;
    int sr = tid >> 2, sc = (tid & 3) * 8;
    int gra = row0 + sr; if (gra >= M) gra = M - 1;

    const int npass = HAS_B2 ? 2 : 1;
    for (int pass = 0; pass < npass; ++pass) {
        const unsigned short* A = pass ? A2 : A1;
        const unsigned short* W = pass ? W1t : W0t;
        for (int k0 = 0; k0 < K; k0 += 64) {
            #pragma unroll
            for (int h = 0; h < 2; ++h) {
                ushort8v va = *reinterpret_cast<const ushort8v*>(&A[(size_t)gra * K + k0 + sc + h * 32]);
                *reinterpret_cast<ushort8v*>(&As[sr * LDT + sc + h * 32]) = va;
            }
            #pragma unroll
            for (int g = 0; g < 2; ++g)
                #pragma unroll
                for (int h = 0; h < 2; ++h) {
                    int r = sr + g * 64;
                    ushort8v vb = *reinterpret_cast<const ushort8v*>(&W[(size_t)(col0 + r) * K + k0 + sc + h * 32]);
                    *reinterpret_cast<ushort8v*>(&Bs[r * LDT + sc + h * 32]) = vb;
                }
            __syncthreads();
            #pragma unroll
            for (int kk = 0; kk < 2; ++kk) {
                int ko = kOff + kk * 32;
                short8v a[2], bb[4];
                #pragma unroll
                for (int i = 0; i < 2; ++i)
                    a[i] = *reinterpret_cast<const short8v*>(&As[(aRow + i * 16) * LDT + ko]);
                #pragma unroll
                for (int i = 0; i < 4; ++i)
                    bb[i] = *reinterpret_cast<const short8v*>(&Bs[(bRow + i * 16) * LDT + ko]);
                #pragma unroll
                for (int mi = 0; mi < 2; ++mi)
                    #pragma unroll
                    for (int ni = 0; ni < 4; ++ni)
                        acc[mi][ni] = __builtin_amdgcn_mfma_f32_16x16x32_bf16(a[mi], bb[ni], acc[mi][ni], 0, 0, 0);
            }
            __syncthreads();
        }
    }

    int colBase = col0 + wn * 64 + (lane & 15);
    int rowSub = (lane >> 4) * 4;
    #pragma unroll
    for (int mi = 0; mi < 2; ++mi) {
        int rowF = row0 + wm * 32 + mi * 16 + rowSub;
        #pragma unroll
        for (int r = 0; r < 4; ++r) {
            int gr = rowF + r;
            if (gr < M) {
                #pragma unroll
                for (int ni = 0; ni < 4; ++ni) {
                    int gc = colBase + ni * 16;
                    float v = acc[mi][ni][r];
                    if (HAS_BIAS) v += bias[gc];
                    if (RELU)     v = fmaxf(v, 0.f);
                    if (ST_BF)    Cb[(size_t)gr * N + gc] = f2bf(v);
                    if (ST_F8)    Cf8[(size_t)gr * N + gc] = f8_1(v);
                }
            }
        }
    }
}

// ---------------- dual GEMM for layer 3 ----------------
// blockIdx.y==0: part = h2@W03 + b3 (fp32); blockIdx.y==1: y3 = h2@W13 (fp8).

template<int K>
__global__ __launch_bounds__(256) void k_gemm_dual(
        const unsigned short* __restrict__ A1, const unsigned short* __restrict__ W03t,
        const unsigned short* __restrict__ W13t, const float* __restrict__ bias,
        float* __restrict__ part, unsigned char* __restrict__ y3f8, int M) {
    const int N = 128;
    __shared__ unsigned short As[64 * LDT];
    __shared__ unsigned short Bs[128 * LDT];
    int tid = threadIdx.x, lane = tid & 63, wave = tid >> 6;
    int wm = wave >> 1, wn = wave & 1;
    int row0 = blockIdx.x * 64;
    const unsigned short* W = blockIdx.y ? W13t : W03t;
    f32x4 acc[2][4];
    #pragma unroll
    for (int i = 0; i < 2; ++i)
        #pragma unroll
        for (int j = 0; j < 4; ++j)
            acc[i][j] = (f32x4){0.f, 0.f, 0.f, 0.f};

    int aRow = wm * 32 + (lane & 15);
    int bRow = wn * 64 + (lane & 15);
    int kOff = (lane >> 4) * 8;
    int sr = tid >> 2, sc = (tid & 3) * 8;
    int gra = row0 + sr; if (gra >= M) gra = M - 1;

    for (int k0 = 0; k0 < K; k0 += 64) {
        #pragma unroll
        for (int h = 0; h < 2; ++h) {
            ushort8v va = *reinterpret_cast<const ushort8v*>(&A1[(size_t)gra * K + k0 + sc + h * 32]);
            *reinterpret_cast<ushort8v*>(&As[sr * LDT + sc + h * 32]) = va;
        }
        #pragma unroll
        for (int g = 0; g < 2; ++g)
            #pragma unroll
            for (int h = 0; h < 2; ++h) {
                int r = sr + g * 64;
                ushort8v vb = *reinterpret_cast<const ushort8v*>(&W[(size_t)r * K + k0 + sc + h * 32]);
                *reinterpret_cast<ushort8v*>(&Bs[r * LDT + sc + h * 32]) = vb;
            }
        __syncthreads();
        #pragma unroll
        for (int kk = 0; kk < 2; ++kk) {
            int ko = kOff + kk * 32;
            short8v a[2], bb[4];
            #pragma unroll
            for (int i = 0; i < 2; ++i)
                a[i] = *reinterpret_cast<const short8v*>(&As[(aRow + i * 16) * LDT + ko]);
            #pragma unroll
            for (int i = 0; i < 4; ++i)
                bb[i] = *reinterpret_cast<const short8v*>(&Bs[(bRow + i * 16) * LDT + ko]);
            #pragma unroll
            for (int mi = 0; mi < 2; ++mi)
                #pragma unroll
                for (int ni = 0; ni < 4; ++ni)
                    acc[mi][ni] = __builtin_amdgcn_mfma_f32_16x16x32_bf16(a[mi], bb[ni], acc[mi][ni], 0, 0, 0);
        }
        __syncthreads();
    }

    int colBase = wn * 64 + (lane & 15);
    int rowSub = (lane >> 4) * 4;
    bool isPart = (blockIdx.y == 0);
    #pragma unroll
    for (int mi = 0; mi < 2; ++mi) {
        int rowF = row0 + wm * 32 + mi * 16 + rowSub;
        #pragma unroll
        for (int r = 0; r < 4; ++r) {
            int gr = rowF + r;
            if (gr < M) {
                #pragma unroll
                for (int ni = 0; ni < 4; ++ni) {
                    int gc = colBase + ni * 16;
                    float v = acc[mi][ni][r];
                    if (isPart) part[(size_t)gr * N + gc] = v + bias[gc];
                    else        y3f8[(size_t)gr * N + gc] = f8_1(v);
                }
            }
        }
    }
}

// ---------------- launch ----------------

extern "C" void kernel_launch(void* const* d_in, const int* in_sizes, int n_in,
                              void* d_out, int out_size, void* d_ws, size_t ws_size,
                              hipStream_t stream) {
    const float* x   = (const float*)d_in[0];
    const int*   ei  = (const int*)d_in[1];
    const float* W01 = (const float*)d_in[3];
    const float* W11 = (const float*)d_in[4];
    const float* b1  = (const float*)d_in[5];
    const float* W02 = (const float*)d_in[6];
    const float* W12 = (const float*)d_in[7];
    const float* b2  = (const float*)d_in[8];
    const float* W03 = (const float*)d_in[9];
    const float* W13 = (const float*)d_in[10];
    const float* b3  = (const float*)d_in[11];
    float* out = (float*)d_out;

    const int n = in_sizes[0] / D_IN;   // 10000
    const int E = in_sizes[1] / 2;      // 640000
    const int* src = ei;
    const int* dst = ei + E;
    const int EPB = (E + HB - 1) / HB;  // 2500

    char* wsb = (char*)d_ws;
    float* dis   = (float*)wsb;                   wsb += NBIN * 4;
    int*   cnt   = (int*)wsb;                     wsb += NBIN * 4;
    int*   off   = (int*)wsb;                     wsb += (NBIN + 16) * 4;
    unsigned short* psrc = (unsigned short*)wsb;  wsb += (size_t)HB * NBIN * 2;
    unsigned short* pdst = (unsigned short*)wsb;  wsb += (size_t)HB * NBIN * 2;
    unsigned* edges = (unsigned*)wsb;             wsb += (size_t)E * 4;
    unsigned short* txb  = (unsigned short*)wsb;  wsb += (size_t)n * D_HID * 2;
    float*          part = (float*)wsb;           wsb += (size_t)n * D_OUT * 4;
    unsigned short* x_bf = (unsigned short*)wsb;  wsb += (size_t)n * D_IN * 2;
    unsigned short* h1_bf = (unsigned short*)wsb; wsb += (size_t)n * D_HID * 2;
    unsigned short* h2_bf = (unsigned short*)wsb; wsb += (size_t)n * D_HID * 2;
    unsigned char* x_f8  = (unsigned char*)wsb;   wsb += (size_t)n * D_IN;
    unsigned char* h1_f8 = (unsigned char*)wsb;   wsb += (size_t)n * D_HID;
    unsigned char* y3_f8 = (unsigned char*)wsb;   wsb += (size_t)n * D_OUT;
    wsb = (char*)(((size_t)wsb + 255) & ~(size_t)255);
    unsigned short* W01t = (unsigned short*)wsb;  wsb += (size_t)D_IN  * D_HID * 2;
    unsigned short* W11t = (unsigned short*)wsb;  wsb += (size_t)D_IN  * D_HID * 2;
    unsigned short* W02t = (unsigned short*)wsb;  wsb += (size_t)D_HID * D_HID * 2;
    unsigned short* W12t = (unsigned short*)wsb;  wsb += (size_t)D_HID * D_HID * 2;
    unsigned short* W03t = (unsigned short*)wsb;  wsb += (size_t)D_HID * D_OUT * 2;
    unsigned short* W13t = (unsigned short*)wsb;  wsb += (size_t)D_HID * D_OUT * 2;

    const int gmx = (n + 63) / 64;      // 157 M-tiles
    const int ga128 = (n + 31) / 32;    // 313 blocks (TPN=8)
    const int ga256 = (n + 15) / 16;    // 625 blocks (TPN=16)

    WtrArgs wa;
    wa.W[0] = W01; wa.T[0] = W01t; wa.K[0] = D_IN;  wa.N[0] = D_HID;
    wa.W[1] = W11; wa.T[1] = W11t; wa.K[1] = D_IN;  wa.N[1] = D_HID;
    wa.W[2] = W02; wa.T[2] = W02t; wa.K[2] = D_HID; wa.N[2] = D_HID;
    wa.W[3] = W12; wa.T[3] = W12t; wa.K[3] = D_HID; wa.N[3] = D_HID;
    wa.W[4] = W03; wa.T[4] = W03t; wa.K[4] = D_HID; wa.N[4] = D_OUT;
    wa.W[5] = W13; wa.T[5] = W13t; wa.K[5] = D_HID; wa.N[5] = D_OUT;
    wa.xin = x; wa.xout = x_bf; wa.xoutf8 = x_f8; wa.nElem = n * D_IN;

    // ---- CSR build (atomic-free) + normalization + conversions ----
    k_hist<<<dim3(HB, 3), 256, 0, stream>>>(src, dst, psrc, pdst, E, EPB, wa);
    k_colsum<<<NBIN / 64, 256, 0, stream>>>(psrc, pdst, dis, cnt);
    k_scan<<<1, 256, 0, stream>>>(cnt, off, n, E);
    k_scatter2<<<HB, 256, 0, stream>>>(src, dst, dis, off, pdst, edges, E, EPB);

    // ---- layer 1: h1 = relu(x@W01 + (A x)@W11 + b1) ----
    k_agg_f8<D_IN, true, false, false><<<ga128, 256, 0, stream>>>(
        off, edges, x_f8, txb, nullptr, nullptr, n);
    k_gemm_mfma<D_IN, true, true, true, true, true><<<dim3(gmx, D_HID / 128), 256, 0, stream>>>(
        x_bf, W01t, txb, W11t, b1, h1_bf, h1_f8, n, D_HID);

    // ---- layer 2: h2 = relu(h1@W02 + (A h1)@W12 + b2) ----
    k_agg_f8<D_HID, true, false, false><<<ga256, 256, 0, stream>>>(
        off, edges, h1_f8, txb, nullptr, nullptr, n);
    k_gemm_mfma<D_HID, true, true, true, true, false><<<dim3(gmx, D_HID / 128), 256, 0, stream>>>(
        h1_bf, W02t, txb, W12t, b2, h2_bf, nullptr, n, D_HID);

    // ---- layer 3: out = (h2@W03 + b3) + A (h2@W13) ----
    k_gemm_dual<D_HID><<<dim3(gmx, 2), 256, 0, stream>>>(
        h2_bf, W03t, W13t, b3, part, y3_f8, n);
    k_agg_f8<D_OUT, false, true, true><<<ga128, 256, 0, stream>>>(
        off, edges, y3_f8, nullptr, out, part, n);
}